// Round 1
// 2201.038 us; speedup vs baseline: 1.2129x; 1.2129x over previous
//
#include <hip/hip_runtime.h>
#include <stdint.h>
#include <math.h>

// ---------------- types ----------------
typedef __bf16 bf16x8_t __attribute__((ext_vector_type(8)));
typedef float  f32x4_t  __attribute__((ext_vector_type(4)));

// ---------------- problem constants (from setup_inputs) ----------------
constexpr int NTOK = 196;           // N tokens
constexpr int DF   = 768;           // D
constexpr int PD   = 64;            // P
constexpr int NSAMP = 1500;         // L*(250+500)
constexpr int SUPS  = 500;          // sup samples (L*250)
constexpr int PFLAT = 2080;         // 64*65/2
constexpr int FTOT  = 7232;         // 2*(768+2080+768)
constexpr size_t FEAT_ELEMS = (size_t)NTOK * DF;   // 150528
constexpr int MROWS  = NSAMP * NTOK;               // 294000 flattened token rows
constexpr int MTILES = (MROWS + 127) / 128;        // 2297
constexpr int BLS_WGS = MTILES * 6;                // 13782

// ---------------- ws layout (bytes) ----------------
constexpr size_t SZ_FEATB = (size_t)NSAMP * FEAT_ELEMS * 2;   // 451,584,000
constexpr size_t OFF_FEATB = 0;
constexpr size_t OFF_WT    = OFF_FEATB + SZ_FEATB;
constexpr size_t SZ_WT     = (size_t)DF * DF * 2;
constexpr size_t OFF_RTH   = OFF_WT + SZ_WT;
constexpr size_t SZ_RT     = (size_t)PD * DF * 2;
constexpr size_t OFF_RTL   = OFF_RTH + SZ_RT;
constexpr size_t OFF_GAP   = OFF_RTL + SZ_RT;
constexpr size_t SZ_GAP    = (size_t)NSAMP * DF * 4;
constexpr size_t OFF_BLS   = OFF_GAP + SZ_GAP;
constexpr size_t OFF_COVF  = OFF_BLS + SZ_GAP;
constexpr size_t SZ_COVF   = (size_t)NSAMP * PFLAT * 4;
constexpr size_t OFF_Z     = OFF_COVF + SZ_COVF;
constexpr size_t SZ_Z      = (size_t)150 * FTOT * 4;
constexpr size_t OFF_ZN    = OFF_Z + SZ_Z;
constexpr size_t OFF_STATS = OFF_ZN + SZ_Z;
constexpr size_t SZ_STATS  = (size_t)4 * 2 * FTOT * 4;
constexpr size_t OFF_KM    = OFF_STATS + SZ_STATS;
constexpr size_t OFF_SIM   = OFF_KM + 5120;

// ---------------- helpers ----------------
__device__ __forceinline__ unsigned short f2bf(float f) {
    unsigned int u = __float_as_uint(f);
    u += 0x7fffu + ((u >> 16) & 1u);     // RNE
    return (unsigned short)(u >> 16);
}
__device__ __forceinline__ float bf2f(unsigned short h) {
    return __uint_as_float(((unsigned int)h) << 16);
}
__device__ __forceinline__ void async_copy16(void* lds, const void* g) {
    __builtin_amdgcn_global_load_lds(
        (const __attribute__((address_space(1))) unsigned int*)g,
        (__attribute__((address_space(3))) unsigned int*)lds, 16, 0, 0);
}
__device__ __forceinline__ f32x4_t mfma16(bf16x8_t a, bf16x8_t b, f32x4_t c) {
    return __builtin_amdgcn_mfma_f32_16x16x32_bf16(a, b, c, 0, 0, 0);
}
__device__ __forceinline__ float tukeyf(float x) {
    float s = (x > 0.f) ? 1.f : ((x < 0.f) ? -1.f : 0.f);
    return s * sqrtf(fabsf(x) + 1e-8f);
}
__device__ __forceinline__ float fast_tanh(float x) {
    // tanh(x) = 1 - 2/(exp(2x)+1); exp under/overflow saturates correctly to -1/+1
    float e = __expf(2.f * x);
    return 1.f - 2.f * __builtin_amdgcn_rcpf(e + 1.f);
}
__device__ __forceinline__ float blockReduceSum(float v, float* scratch) {
    for (int m = 1; m < 64; m <<= 1) v += __shfl_xor(v, m);
    int w = threadIdx.x >> 6, lane = threadIdx.x & 63;
    if (lane == 0) scratch[w] = v;
    __syncthreads();
    float r = scratch[0] + scratch[1] + scratch[2] + scratch[3];
    __syncthreads();
    return r;
}

// ================= K1: transpose W (bf16) and cov_reducer (bf16 hi/lo); zero blsB =================
__global__ __launch_bounds__(256) void k_prep(const float* __restrict__ W,
                                              const float* __restrict__ red,
                                              unsigned short* __restrict__ Wt,
                                              unsigned short* __restrict__ rTh,
                                              unsigned short* __restrict__ rTl,
                                              float* __restrict__ blsB) {
    int tid = blockIdx.x * 256 + threadIdx.x;
    int stride = gridDim.x * 256;
    for (int idx = tid; idx < DF * DF; idx += stride) {
        int d = idx / DF, k = idx % DF;
        Wt[idx] = f2bf(W[k * DF + d]);          // Wt[d][k] = W[k][d]
    }
    for (int idx = tid; idx < PD * DF; idx += stride) {
        int p = idx / DF, k = idx % DF;
        float v = red[k * PD + p];               // redT[p][k] = red[k][p]
        unsigned short h = f2bf(v);
        rTh[idx] = h;
        rTl[idx] = f2bf(v - bf2f(h));
    }
    for (int idx = tid; idx < NSAMP * DF; idx += stride) blsB[idx] = 0.f;  // k_bls accumulates via atomics
}

// ================= K3: per-sample fused: gap + bf16 copy + x proj (bf16x3 MFMA) + cov + Newton-Schulz =================
__global__ __launch_bounds__(256) void k_sample(const float* __restrict__ fsup,
                                                const float* __restrict__ fqry,
                                                const unsigned short* __restrict__ rTh,
                                                const unsigned short* __restrict__ rTl,
                                                unsigned short* __restrict__ featB,
                                                float* __restrict__ gapB,
                                                float* __restrict__ covF) {
    __shared__ __align__(16) char smem[67840];
    unsigned short* Ahi = (unsigned short*)smem;          // [256][32]
    unsigned short* Alo = Ahi + 8192;
    unsigned short* Bhi = Alo + 8192;                     // [64][32]
    unsigned short* Blo = Bhi + 2048;
    float* xT    = (float*)smem;                          // [64][197] (aliases staging)
    float* covB  = (float*)(smem + 50432);                // [64][65]
    float* gscr  = (float*)(smem + 50432 + 16640);        // 128 f
    float* means = (float*)(smem + 50432 + 16640 + 512);  // 64 f

    int sid = blockIdx.x;
    const float* fbase = (sid < SUPS) ? (fsup + (size_t)sid * FEAT_ELEMS)
                                      : (fqry + (size_t)(sid - SUPS) * FEAT_ELEMS);
    unsigned short* fB = featB + (size_t)sid * FEAT_ELEMS;

    int t = threadIdx.x;
    int w = t >> 6, lane = t & 63;
    int kgroup = t & 7, rbase = t >> 3;    // staging: 32 rows x (8 groups of 4 cols)

    f32x4_t acc[4][4];
    f32x4_t z4 = {0.f, 0.f, 0.f, 0.f};
    #pragma unroll
    for (int i = 0; i < 4; ++i)
        #pragma unroll
        for (int j = 0; j < 4; ++j) acc[i][j] = z4;

    for (int k0 = 0; k0 < DF; k0 += 32) {
        // ---- stage A (256 padded rows x 32k), compute gap partials, write bf16 copy ----
        float gx = 0.f, gy = 0.f, gz = 0.f, gw = 0.f;
        #pragma unroll
        for (int it = 0; it < 8; ++it) {
            int row = rbase + 32 * it;
            int n = row < NTOK ? row : (NTOK - 1);
            float4 v = *(const float4*)(fbase + (size_t)n * DF + k0 + kgroup * 4);
            unsigned short h0 = f2bf(v.x), h1 = f2bf(v.y), h2 = f2bf(v.z), h3 = f2bf(v.w);
            ushort4 hv; hv.x = h0; hv.y = h1; hv.z = h2; hv.w = h3;
            ushort4 lv;
            lv.x = f2bf(v.x - bf2f(h0)); lv.y = f2bf(v.y - bf2f(h1));
            lv.z = f2bf(v.z - bf2f(h2)); lv.w = f2bf(v.w - bf2f(h3));
            *(ushort4*)(Ahi + row * 32 + kgroup * 4) = hv;
            *(ushort4*)(Alo + row * 32 + kgroup * 4) = lv;
            if (row < NTOK) {
                gx += v.x; gy += v.y; gz += v.z; gw += v.w;
                *(ushort4*)(fB + (size_t)row * DF + k0 + kgroup * 4) = hv;
            }
        }
        gx += __shfl_xor(gx, 8);  gy += __shfl_xor(gy, 8);  gz += __shfl_xor(gz, 8);  gw += __shfl_xor(gw, 8);
        gx += __shfl_xor(gx, 16); gy += __shfl_xor(gy, 16); gz += __shfl_xor(gz, 16); gw += __shfl_xor(gw, 16);
        gx += __shfl_xor(gx, 32); gy += __shfl_xor(gy, 32); gz += __shfl_xor(gz, 32); gw += __shfl_xor(gw, 32);
        if (lane < 8) {
            gscr[w * 32 + lane * 4 + 0] = gx; gscr[w * 32 + lane * 4 + 1] = gy;
            gscr[w * 32 + lane * 4 + 2] = gz; gscr[w * 32 + lane * 4 + 3] = gw;
        }
        // ---- stage B (redT hi/lo 64x32) ----
        {
            int p = t >> 2, kq = t & 3;
            *(bf16x8_t*)(Bhi + p * 32 + kq * 8) = *(const bf16x8_t*)(rTh + (size_t)p * DF + k0 + kq * 8);
            *(bf16x8_t*)(Blo + p * 32 + kq * 8) = *(const bf16x8_t*)(rTl + (size_t)p * DF + k0 + kq * 8);
        }
        __syncthreads();
        // gap write (complete for these 32 columns)
        if (t < 32) {
            float s = gscr[t] + gscr[32 + t] + gscr[64 + t] + gscr[96 + t];
            gapB[(size_t)sid * DF + k0 + t] = s * (1.f / 196.f);
        }
        // ---- fragments + bf16x3 MFMA ----
        bf16x8_t ah[4], al[4], bh[4], bl[4];
        int krow = (lane >> 4) * 8;
        #pragma unroll
        for (int i = 0; i < 4; ++i) {
            int aoff = (w * 64 + i * 16 + (lane & 15)) * 32 + krow;
            ah[i] = *(const bf16x8_t*)&Ahi[aoff];
            al[i] = *(const bf16x8_t*)&Alo[aoff];
        }
        #pragma unroll
        for (int j = 0; j < 4; ++j) {
            int boff = (j * 16 + (lane & 15)) * 32 + krow;
            bh[j] = *(const bf16x8_t*)&Bhi[boff];
            bl[j] = *(const bf16x8_t*)&Blo[boff];
        }
        #pragma unroll
        for (int i = 0; i < 4; ++i)
            #pragma unroll
            for (int j = 0; j < 4; ++j) {
                acc[i][j] = mfma16(ah[i], bh[j], acc[i][j]);
                acc[i][j] = mfma16(ah[i], bl[j], acc[i][j]);
                acc[i][j] = mfma16(al[i], bh[j], acc[i][j]);
            }
        __syncthreads();
    }

    // ---- write xT[p][n] (transposed, stride 197) ----
    int quad = lane >> 4, col = lane & 15;
    #pragma unroll
    for (int i = 0; i < 4; ++i)
        #pragma unroll
        for (int j = 0; j < 4; ++j)
            #pragma unroll
            for (int r = 0; r < 4; ++r) {
                int rowN = w * 64 + i * 16 + quad * 4 + r;
                if (rowN < NTOK) xT[(j * 16 + col) * 197 + rowN] = acc[i][j][r];
            }
    __syncthreads();
    // ---- center columns ----
    if (t < 64) {
        float s = 0.f;
        for (int n = 0; n < NTOK; ++n) s += xT[t * 197 + n];
        means[t] = s * (1.f / 196.f);
    }
    __syncthreads();
    {
        int p = t & 63;
        for (int n = t >> 6; n < NTOK; n += 4) xT[p * 197 + n] -= means[p];
    }
    __syncthreads();
    // ---- cov = xT*xT^T/195 + 1e-5 I ; frobenius norm ----
    int tp = t >> 4, tq = t & 15;
    {
        float cc[4][4] = {{0.f}};
        for (int k = 0; k < NTOK; ++k) {
            float a_[4], b_[4];
            #pragma unroll
            for (int i = 0; i < 4; ++i) a_[i] = xT[(4 * tp + i) * 197 + k];
            #pragma unroll
            for (int j = 0; j < 4; ++j) b_[j] = xT[(4 * tq + j) * 197 + k];
            #pragma unroll
            for (int i = 0; i < 4; ++i)
                #pragma unroll
                for (int j = 0; j < 4; ++j) cc[i][j] += a_[i] * b_[j];
        }
        float ssq = 0.f;
        #pragma unroll
        for (int i = 0; i < 4; ++i)
            #pragma unroll
            for (int j = 0; j < 4; ++j) {
                int gi = 4 * tp + i, gj = 4 * tq + j;
                float cv = cc[i][j] * (1.f / 195.f);
                if (gi == gj) cv += 1e-5f;
                covB[gi * 65 + gj] = cv;
                ssq += cv * cv;
            }
        float tot = blockReduceSum(ssq, gscr);
        float norm = sqrtf(tot);
        float rn = 1.f / (norm + 1e-8f);
        float scs = sqrtf(norm + 1e-8f);
        // ---- Newton-Schulz (3 iters), buffers stride 65 ----
        float* Yp = xT;            // slot0
        float* Zp = xT + 4160;     // slot1
        float* Up = xT + 8320;     // slot2
        float* Tp = covB;
        for (int e = 0; e < 16; ++e) {
            int idx = t + 256 * e;
            int i = idx >> 6, j = idx & 63;
            Yp[i * 65 + j] = covB[i * 65 + j] * rn;
            Zp[i * 65 + j] = (i == j) ? 1.f : 0.f;
        }
        __syncthreads();

        for (int itn = 0; itn < 3; ++itn) {
            // T = 0.5*(3I - Z@Y)
            {
                float dd[4][4] = {{0.f}};
                for (int k = 0; k < 64; ++k) {
                    float a_[4], b_[4];
                    #pragma unroll
                    for (int i = 0; i < 4; ++i) a_[i] = Zp[(4 * tp + i) * 65 + k];
                    #pragma unroll
                    for (int j = 0; j < 4; ++j) b_[j] = Yp[k * 65 + 4 * tq + j];
                    #pragma unroll
                    for (int i = 0; i < 4; ++i)
                        #pragma unroll
                        for (int j = 0; j < 4; ++j) dd[i][j] += a_[i] * b_[j];
                }
                #pragma unroll
                for (int i = 0; i < 4; ++i)
                    #pragma unroll
                    for (int j = 0; j < 4; ++j) {
                        int gi = 4 * tp + i, gj = 4 * tq + j;
                        Tp[gi * 65 + gj] = 0.5f * (((gi == gj) ? 3.f : 0.f) - dd[i][j]);
                    }
            }
            __syncthreads();
            // U = Y@T
            {
                float dd[4][4] = {{0.f}};
                for (int k = 0; k < 64; ++k) {
                    float a_[4], b_[4];
                    #pragma unroll
                    for (int i = 0; i < 4; ++i) a_[i] = Yp[(4 * tp + i) * 65 + k];
                    #pragma unroll
                    for (int j = 0; j < 4; ++j) b_[j] = Tp[k * 65 + 4 * tq + j];
                    #pragma unroll
                    for (int i = 0; i < 4; ++i)
                        #pragma unroll
                        for (int j = 0; j < 4; ++j) dd[i][j] += a_[i] * b_[j];
                }
                #pragma unroll
                for (int i = 0; i < 4; ++i)
                    #pragma unroll
                    for (int j = 0; j < 4; ++j) Up[(4 * tp + i) * 65 + 4 * tq + j] = dd[i][j];
            }
            __syncthreads();
            // Z' = T@Z  (into old Y buffer)
            {
                float dd[4][4] = {{0.f}};
                for (int k = 0; k < 64; ++k) {
                    float a_[4], b_[4];
                    #pragma unroll
                    for (int i = 0; i < 4; ++i) a_[i] = Tp[(4 * tp + i) * 65 + k];
                    #pragma unroll
                    for (int j = 0; j < 4; ++j) b_[j] = Zp[k * 65 + 4 * tq + j];
                    #pragma unroll
                    for (int i = 0; i < 4; ++i)
                        #pragma unroll
                        for (int j = 0; j < 4; ++j) dd[i][j] += a_[i] * b_[j];
                }
                #pragma unroll
                for (int i = 0; i < 4; ++i)
                    #pragma unroll
                    for (int j = 0; j < 4; ++j) Yp[(4 * tp + i) * 65 + 4 * tq + j] = dd[i][j];
            }
            __syncthreads();
            float* ny = Up; float* nz = Yp; float* nu = Zp;
            Yp = ny; Zp = nz; Up = nu;
        }
        // ---- upper-triangle write: cs = Y*sqrt(norm+1e-8) ----
        for (int idx = t; idx < PFLAT; idx += 256) {
            float disc = 129.f * 129.f - 8.f * (float)idx;
            int i = (int)((129.f - sqrtf(disc)) * 0.5f);
            if (i > 63) i = 63; if (i < 0) i = 0;
            while (i < 63 && ((i + 1) * 64 - ((i + 1) * i) / 2) <= idx) ++i;
            while (i > 0 && (i * 64 - (i * (i - 1)) / 2) > idx) --i;
            int S = i * 64 - (i * (i - 1)) / 2;
            int j = idx - S + i;
            covF[(size_t)sid * PFLAT + idx] = Yp[i * 65 + j] * scs;
        }
    }
}

// ================= K2: bls GEMM  tanh(feat@W + b).mean(n) =================
// Flattened-M (294000 token rows) 128x128 tiles, depth-1 double-buffered LDS with
// counted-drain (raw s_barrier, loads issued BEFORE compute so latency hides under MFMA),
// XOR chunk-swizzled staging (conflict-free ds_read_b128), XCD-chunked block swizzle.
__global__ __launch_bounds__(256, 4) void k_bls(const unsigned short* __restrict__ featB,
                                                const unsigned short* __restrict__ Wt,
                                                const float* __restrict__ b_bls,
                                                float* __restrict__ blsB) {
    __shared__ __align__(16) unsigned short Al[2][128 * 32];
    __shared__ __align__(16) unsigned short Bl[2][128 * 32];

    // bijective XCD-chunked swizzle: 6 consecutive logical blocks (same A m-tile) -> same XCD L2
    constexpr int nwg = BLS_WGS;                 // 13782
    constexpr int q = nwg >> 3, rr = nwg & 7;    // 1722, 6
    int xcd = blockIdx.x & 7, bidx = blockIdx.x >> 3;
    int logical = (xcd < rr ? xcd * (q + 1) : rr * (q + 1) + (xcd - rr) * q) + bidx;
    int mtile = logical / 6, dt = logical % 6;
    int R0 = mtile * 128;
    int d0 = dt * 128;

    int t = threadIdx.x;
    int w = t >> 6, lane = t & 63;
    int wm = w >> 1, wn = w & 1;
    int col = lane & 15, g = lane >> 4, quad = lane >> 4;

    f32x4_t acc[4][4];
    f32x4_t z4 = {0.f, 0.f, 0.f, 0.f};
    #pragma unroll
    for (int i = 0; i < 4; ++i)
        #pragma unroll
        for (int j = 0; j < 4; ++j) acc[i][j] = z4;

    // stage one 128x32 A tile + 128x32 B tile (bf16) into buf; 4 global_load_lds / thread.
    // LDS dest is LINEAR (cid*16B, wave-uniform base + lane*16); the k-chunk swizzle is
    // applied on the GLOBAL source: chunk_g = chunk_lds ^ ((row>>1)&3)  (involution).
    auto stage = [&](int buf, int k0) {
        #pragma unroll
        for (int l = 0; l < 2; ++l) {
            int cid = l * 256 + t;                    // 0..511 : (row<<2)|chunk
            int r = cid >> 2;                         // tile row 0..127
            int cg = (cid & 3) ^ ((r >> 1) & 3);      // swizzled global k-chunk
            int Rg = R0 + r; if (Rg >= MROWS) Rg = MROWS - 1;
            async_copy16((char*)&Al[buf][0] + (size_t)cid * 16,
                         featB + (size_t)Rg * DF + k0 + cg * 8);
            async_copy16((char*)&Bl[buf][0] + (size_t)cid * 16,
                         Wt + (size_t)(d0 + r) * DF + k0 + cg * 8);
        }
    };

    stage(0, 0);
    asm volatile("s_waitcnt vmcnt(0)" ::: "memory");
    __builtin_amdgcn_s_barrier();

    // read-side swizzled chunk offset: row = 16*m + col  =>  sw(row) = (col>>1)&3 (row-bits 4+ drop out)
    int swc = (g ^ ((col >> 1) & 3)) * 8;   // shorts
    int cur = 0;
    for (int ks = 0; ks < DF / 32; ++ks) {
        if (ks + 1 < DF / 32) stage(cur ^ 1, (ks + 1) * 32);   // prefetch next K-step
        bf16x8_t af[4], bfr[4];
        #pragma unroll
        for (int i = 0; i < 4; ++i)
            af[i] = *(const bf16x8_t*)&Al[cur][(wm * 64 + i * 16 + col) * 32 + swc];
        #pragma unroll
        for (int j = 0; j < 4; ++j)
            bfr[j] = *(const bf16x8_t*)&Bl[cur][(wn * 64 + j * 16 + col) * 32 + swc];
        #pragma unroll
        for (int i = 0; i < 4; ++i)
            #pragma unroll
            for (int j = 0; j < 4; ++j)
                acc[i][j] = mfma16(af[i], bfr[j], acc[i][j]);
        if (ks + 1 < DF / 32) {
            asm volatile("s_waitcnt vmcnt(0)" ::: "memory");   // next-tile loads landed (hidden under MFMA)
            __builtin_amdgcn_s_barrier();                      // all waves done reading buf[cur]
            cur ^= 1;
        }
    }

    // epilogue: tanh + per-sample masked column sums -> global atomics (tile spans <=2 samples)
    int sid0 = R0 / NTOK;
    int bnd = sid0 * NTOK + NTOK;        // first row of sid0+1
    #pragma unroll
    for (int j = 0; j < 4; ++j) {
        int d = d0 + wn * 64 + j * 16 + col;
        float bb = b_bls[d];
        float p0 = 0.f, p1 = 0.f;
        #pragma unroll
        for (int i = 0; i < 4; ++i)
            #pragma unroll
            for (int r = 0; r < 4; ++r) {
                int Rg = R0 + wm * 64 + i * 16 + quad * 4 + r;
                if (Rg < MROWS) {
                    float v = fast_tanh(acc[i][j][r] + bb);
                    if (Rg < bnd) p0 += v; else p1 += v;
                }
            }
        p0 += __shfl_xor(p0, 16); p0 += __shfl_xor(p0, 32);
        p1 += __shfl_xor(p1, 16); p1 += __shfl_xor(p1, 32);
        if (quad == 0) {
            if (p0 != 0.f) atomicAdd(&blsB[(size_t)sid0 * DF + d], p0 * (1.f / 196.f));
            if (p1 != 0.f && sid0 + 1 < NSAMP)
                atomicAdd(&blsB[(size_t)(sid0 + 1) * DF + d], p1 * (1.f / 196.f));
        }
    }
}

// ================= K5: fuse (view-mean -> tukey -> per-component l2norm*w) =================
__global__ __launch_bounds__(256) void k_fuse(const float* __restrict__ gapB,
                                              const float* __restrict__ covF,
                                              const float* __restrict__ blsB,
                                              float* __restrict__ z) {
    __shared__ float zrow[FTOT];
    __shared__ float scr[8];
    int r = blockIdx.x, t = threadIdx.x;
    bool isSup = r < 50;
    int g = isSup ? r : r - 50;

    float ss0 = 0.f, ss1 = 0.f, ss2 = 0.f;
    for (int f = t; f < DF; f += 256) {
        for (int l = 0; l < 2; ++l) {
            float s = 0.f;
            for (int v = 0; v < 5; ++v) {
                int sid = isSup ? (l * 250 + g * 5 + v) : (500 + l * 500 + g * 5 + v);
                s += gapB[(size_t)sid * DF + f];
            }
            float tk = tukeyf(s * 0.2f);
            zrow[l * DF + f] = tk;
            ss0 += tk * tk;
        }
    }
    for (int f = t; f < PFLAT; f += 256) {
        for (int l = 0; l < 2; ++l) {
            float s = 0.f;
            for (int v = 0; v < 5; ++v) {
                int sid = isSup ? (l * 250 + g * 5 + v) : (500 + l * 500 + g * 5 + v);
                s += covF[(size_t)sid * PFLAT + f];
            }
            float tk = tukeyf(s * 0.2f);
            zrow[1536 + l * PFLAT + f] = tk;
            ss1 += tk * tk;
        }
    }
    for (int f = t; f < DF; f += 256) {
        for (int l = 0; l < 2; ++l) {
            float s = 0.f;
            for (int v = 0; v < 5; ++v) {
                int sid = isSup ? (l * 250 + g * 5 + v) : (500 + l * 500 + g * 5 + v);
                s += blsB[(size_t)sid * DF + f];
            }
            float tk = tukeyf(s * 0.2f);
            zrow[5696 + l * DF + f] = tk;
            ss2 += tk * tk;
        }
    }
    __syncthreads();
    float n0 = blockReduceSum(ss0, scr);
    float n1 = blockReduceSum(ss1, scr);
    float n2 = blockReduceSum(ss2, scr);
    float s0 = 1.0f / fmaxf(sqrtf(n0), 1e-12f);
    float s1 = 0.8f / fmaxf(sqrtf(n1), 1e-12f);
    float s2 = 0.1f / fmaxf(sqrtf(n2), 1e-12f);
    for (int f = t; f < FTOT; f += 256) {
        float sc = (f < 1536) ? s0 : ((f < 5696) ? s1 : s2);
        z[(size_t)r * FTOT + f] = zrow[f] * sc;
    }
}

// ================= K6a: per-(b,f) mu/std (ddof=1) over sup and qry =================
__global__ __launch_bounds__(256) void k_stats(const float* __restrict__ z,
                                               float* __restrict__ stats) {
    int f = blockIdx.x * 256 + threadIdx.x;
    int b = blockIdx.y;
    if (f >= FTOT) return;
    float mu = 0.f;
    for (int i = 0; i < 25; ++i) mu += z[(size_t)(b * 25 + i) * FTOT + f];
    mu *= (1.f / 25.f);
    float var = 0.f;
    for (int i = 0; i < 25; ++i) { float d = z[(size_t)(b * 25 + i) * FTOT + f] - mu; var += d * d; }
    float sds = sqrtf(var * (1.f / 24.f)) + 1e-8f;
    float muq = 0.f;
    for (int q = 0; q < 50; ++q) muq += z[(size_t)(50 + b * 50 + q) * FTOT + f];
    muq *= (1.f / 50.f);
    float varq = 0.f;
    for (int q = 0; q < 50; ++q) { float d = z[(size_t)(50 + b * 50 + q) * FTOT + f] - muq; varq += d * d; }
    float sdq = sqrtf(varq * (1.f / 49.f)) + 1e-8f;
    stats[(0 * 2 + b) * FTOT + f] = mu;
    stats[(1 * 2 + b) * FTOT + f] = sds;
    stats[(2 * 2 + b) * FTOT + f] = muq;
    stats[(3 * 2 + b) * FTOT + f] = sdq;
}

// ================= K6b: standardize-transfer + l2norm =================
__global__ __launch_bounds__(256) void k_norm2(const float* __restrict__ z,
                                               const float* __restrict__ stats,
                                               float* __restrict__ zn) {
    __shared__ float scr[8];
    int r = blockIdx.x, t = threadIdx.x;
    bool isSup = r < 50;
    int b = isSup ? (r / 25) : ((r - 50) / 50);
    const float* mu_s = stats + (size_t)(0 * 2 + b) * FTOT;
    const float* sd_s = stats + (size_t)(1 * 2 + b) * FTOT;
    const float* mu_q = stats + (size_t)(2 * 2 + b) * FTOT;
    const float* sd_q = stats + (size_t)(3 * 2 + b) * FTOT;
    float ssq = 0.f;
    for (int f = t; f < FTOT; f += 256) {
        float v;
        float zv = z[(size_t)r * FTOT + f];
        if (isSup) v = zv - mu_s[f];
        else {
            float q = (zv - mu_q[f]) / sd_q[f] * sd_s[f] + mu_s[f];  // replicate ref exactly
            v = q - mu_s[f];
        }
        zn[(size_t)r * FTOT + f] = v;
        ssq += v * v;
    }
    float tot = blockReduceSum(ssq, scr);
    float sc = 1.f / fmaxf(sqrtf(tot), 1e-12f);
    for (int f = t; f < FTOT; f += 256) zn[(size_t)r * FTOT + f] *= sc;
}

// ================= K7: gram K and sim =================
__global__ __launch_bounds__(256) void k_gram(const float* __restrict__ zn,
                                              float* __restrict__ Km,
                                              float* __restrict__ simB) {
    __shared__ float scr[8];
    int r = blockIdx.x, t = threadIdx.x;
    bool isSup = r < 50;
    int b = isSup ? (r / 25) : ((r - 50) / 50);
    const float* a = zn + (size_t)r * FTOT;
    for (int j = 0; j < 25; ++j) {
        const float* bj = zn + (size_t)(b * 25 + j) * FTOT;
        float p = 0.f;
        for (int f = t; f < FTOT; f += 256) p += a[f] * bj[f];
        float tot = blockReduceSum(p, scr);
        if (t == 0) {
            if (isSup) Km[b * 625 + (r - b * 25) * 25 + j] = tot;
            else       simB[b * 1250 + (r - 50 - b * 50) * 25 + j] = tot;
        }
    }
}

// ================= K8: ridge solve + output =================
__global__ __launch_bounds__(256) void k_solve(const float* __restrict__ Km,
                                               const float* __restrict__ simB,
                                               const int* __restrict__ y_sup,
                                               float* __restrict__ out) {
    __shared__ float A[25][31];
    __shared__ float alpha[25][5];
    int b = blockIdx.x, t = threadIdx.x;
    const float lam = 0.1f * (7232.0f / 500.0f);
    for (int idx = t; idx < 625; idx += 256) {
        int i = idx / 25, j = idx % 25;
        A[i][j] = Km[b * 625 + idx] + ((i == j) ? lam : 0.f);
    }
    for (int idx = t; idx < 125; idx += 256) {
        int i = idx / 5, c = idx % 5;
        A[i][25 + c] = (y_sup[b * 25 + i] == c) ? 1.f : 0.f;
    }
    __syncthreads();
    for (int k = 0; k < 25; ++k) {
        if (t > k && t < 25) {
            float f = A[t][k] / A[k][k];
            for (int c = k; c < 30; ++c) A[t][c] -= f * A[k][c];
        }
        __syncthreads();
    }
    for (int k = 24; k >= 0; --k) {
        if (t < 5) {
            float s = A[k][25 + t];
            for (int j = k + 1; j < 25; ++j) s -= A[k][j] * alpha[j][t];
            alpha[k][t] = s / A[k][k];
        }
        __syncthreads();
    }
    for (int idx = t; idx < 250; idx += 256) {
        int q = idx / 5, c = idx % 5;
        float s = 0.f;
        for (int n = 0; n < 25; ++n) s += simB[b * 1250 + q * 25 + n] * alpha[n][c];
        out[(b * 50 + q) * 5 + c] = 20.f * s;
    }
}

// ================= launcher =================
extern "C" void kernel_launch(void* const* d_in, const int* in_sizes, int n_in,
                              void* d_out, int out_size, void* d_ws, size_t ws_size,
                              hipStream_t stream) {
    const float* fsup  = (const float*)d_in[0];
    const float* fqry  = (const float*)d_in[1];
    const float* red   = (const float*)d_in[2];
    const float* Wb    = (const float*)d_in[3];
    const float* b_bls = (const float*)d_in[4];
    const int*   y_sup = (const int*)d_in[5];
    float* out = (float*)d_out;
    char* ws = (char*)d_ws;

    unsigned short* featB = (unsigned short*)(ws + OFF_FEATB);
    unsigned short* Wt    = (unsigned short*)(ws + OFF_WT);
    unsigned short* rTh   = (unsigned short*)(ws + OFF_RTH);
    unsigned short* rTl   = (unsigned short*)(ws + OFF_RTL);
    float* gapB  = (float*)(ws + OFF_GAP);
    float* blsB  = (float*)(ws + OFF_BLS);
    float* covF  = (float*)(ws + OFF_COVF);
    float* z     = (float*)(ws + OFF_Z);
    float* zn    = (float*)(ws + OFF_ZN);
    float* stats = (float*)(ws + OFF_STATS);
    float* Km    = (float*)(ws + OFF_KM);
    float* simB  = (float*)(ws + OFF_SIM);

    k_prep<<<dim3(512), dim3(256), 0, stream>>>(Wb, red, Wt, rTh, rTl, blsB);
    k_sample<<<dim3(NSAMP), dim3(256), 0, stream>>>(fsup, fqry, rTh, rTl, featB, gapB, covF);
    k_bls<<<dim3(BLS_WGS), dim3(256), 0, stream>>>(featB, Wt, b_bls, blsB);
    k_fuse<<<dim3(150), dim3(256), 0, stream>>>(gapB, covF, blsB, z);
    k_stats<<<dim3((FTOT + 255) / 256, 2), dim3(256), 0, stream>>>(z, stats);
    k_norm2<<<dim3(150), dim3(256), 0, stream>>>(z, stats, zn);
    k_gram<<<dim3(150), dim3(256), 0, stream>>>(zn, Km, simB);
    k_solve<<<dim3(2), dim3(256), 0, stream>>>(Km, simB, y_sup, out);
}